// Round 5
// baseline (486.896 us; speedup 1.0000x reference)
//
#include <hip/hip_runtime.h>

#define NROWS 262144
#define MT 128                  // rows per block = 8 waves x 16 rows
#define NBLK (NROWS / MT)       // 2048 exact
#define EPSV 1e-5f

typedef __attribute__((ext_vector_type(8))) short short8;
typedef __attribute__((ext_vector_type(4))) short shortx4;
typedef __attribute__((ext_vector_type(4))) float floatx4;
typedef __attribute__((ext_vector_type(2))) float floatx2;
typedef __attribute__((ext_vector_type(4))) unsigned int uintx4;

__device__ __forceinline__ unsigned short f2bf(float f) {
    unsigned u = __builtin_bit_cast(unsigned, f);
    u += 0x7fff + ((u >> 16) & 1);
    return (unsigned short)(u >> 16);
}
__device__ __forceinline__ float bf2f(short s) {
    unsigned u = ((unsigned)(unsigned short)s) << 16;
    return __builtin_bit_cast(float, u);
}
__device__ __forceinline__ unsigned cvtpk(float a, float b) {
    unsigned r;
    asm("v_cvt_pk_bf16_f32 %0, %1, %2" : "=v"(r) : "v"(a), "v"(b));
    return r;
}
__device__ __forceinline__ floatx2 pk_add(floatx2 a, floatx2 b) {
    floatx2 d; asm("v_pk_add_f32 %0, %1, %2" : "=v"(d) : "v"(a), "v"(b)); return d;
}
__device__ __forceinline__ floatx2 pk_mul(floatx2 a, floatx2 b) {
    floatx2 d; asm("v_pk_mul_f32 %0, %1, %2" : "=v"(d) : "v"(a), "v"(b)); return d;
}
__device__ __forceinline__ floatx2 pk_fma(floatx2 a, floatx2 b, floatx2 c) {
    floatx2 d; asm("v_pk_fma_f32 %0, %1, %2, %3" : "=v"(d) : "v"(a), "v"(b), "v"(c)); return d;
}
// DPP row_shr add: after {1,2,4,8} lane l16==15 of each 16-group holds the sum
template<int C>
__device__ __forceinline__ float dpp_add(float v) {
    int t = __builtin_amdgcn_update_dpp(0, __builtin_bit_cast(int, v), C, 0xf, 0xf, true);
    return v + __builtin_bit_cast(float, t);
}
__device__ __forceinline__ float red16(float v) {
    v = dpp_add<0x111>(v);
    v = dpp_add<0x112>(v);
    v = dpp_add<0x114>(v);
    v = dpp_add<0x118>(v);
    return v;
}
// broadcast lane 15 of each 16-lane group to all 16 lanes (ds_swizzle BitMode:
// src = (lane & 0x10) | 0xF  -> offset = (0xF<<5)|0x10 = 0x1F0)
__device__ __forceinline__ float bcast15(float v) {
    return __builtin_bit_cast(float,
        __builtin_amdgcn_ds_swizzle(__builtin_bit_cast(int, v), 0x01F0));
}
// async global->LDS, 16B per lane (dest = wave-uniform base + lane*16)
__device__ __forceinline__ void gload16(const short* g, short* l) {
    __builtin_amdgcn_global_load_lds(
        (const __attribute__((address_space(1))) unsigned int*)g,
        (__attribute__((address_space(3))) unsigned int*)l, 16, 0, 0);
}

// ===== R5 weight layout: flat chunk stream, chunk = 8 nt-tiles x 1 k'-slice =====
// chunk(stage, ncg, ks) holds B[k'][n] for k' in [ks*32,ks*32+32), n in
// [ncg*128 + ntl*16 + l16]; within chunk: [ntl(8)][lane(64)][j(8)] lane-ordered.
// K-PERMUTATION (stages 2,3): position k' = ks*32 + q*8 + j holds ACTUAL
// k = (q*8+j)*16 + ks  (matches A-scratch layout k' = l16w*32 + nt, value =
// h[row][nt*16+l16w]).  Stage-1 (A = z, unpermuted): actual k = k'.
// Stream order = consumption order: w1[ncg4][ks2] | w2[ncg4][ks16] | wh1[ncg2][ks16].
__global__ void convert_weights(const float* __restrict__ W1, const float* __restrict__ W2,
                                const float* __restrict__ Wh1, short* __restrict__ ws) {
    int idx = blockIdx.x * 256 + threadIdx.x;
    if (idx < 32768) {
        int j = idx & 7, lane = (idx >> 3) & 63, c = idx >> 9;      // c 0..63
        int ntl = c & 7, ks = (c >> 3) & 1, ncg = c >> 4;           // ncg 0..3
        int q = lane >> 4, l16 = lane & 15;
        int k = ks * 32 + q * 8 + j;                                // unpermuted
        int n = ncg * 128 + ntl * 16 + l16;
        ws[idx] = (short)f2bf(W1[k * 512 + n]);
    } else if (idx < 32768 + 262144) {
        int jdx = idx - 32768;
        int j = jdx & 7, lane = (jdx >> 3) & 63, c = jdx >> 9;      // c 0..511
        int ntl = c & 7, ks = (c >> 3) & 15, ncg = c >> 7;          // ncg 0..3
        int q = lane >> 4, l16 = lane & 15;
        int k = (q * 8 + j) * 16 + ks;                              // permuted
        int n = ncg * 128 + ntl * 16 + l16;
        ws[idx] = (short)f2bf(W2[k * 512 + n]);
    } else if (idx < 32768 + 262144 + 131072) {
        int jdx = idx - (32768 + 262144);
        int j = jdx & 7, lane = (jdx >> 3) & 63, c = jdx >> 9;      // c 0..255
        int ntl = c & 7, ks = (c >> 3) & 15, ncg = c >> 7;          // ncg 0..1
        int q = lane >> 4, l16 = lane & 15;
        int k = (q * 8 + j) * 16 + ks;                              // permuted
        int d = ncg * 128 + ntl * 16 + l16;                         // 0..255
        int kk = d >> 6, dd = d & 63;
        ws[idx] = (short)f2bf(Wh1[(kk * 512 + k) * 64 + dd]);
    }
}

// R5: M-split restructure. 512 threads = 8 waves; wave owns 16 rows x 512 cols.
// B staged once per block into LDS (2-phase chunk pipeline, 104 chunks x 8KB),
// all waves consume the shared copy -> weight L2 traffic/CU 13.3MB -> 6.4MB.
// LN fully wave-local (DPP reduce + ds_swizzle bcast): zero LN barriers.
// A-scratch wave-private 16KB (XOR-swizzled, k'-permuted so LN writes are b128).
// acc 128 AGPR + ~110 VGPR -> 2 waves/SIMD; LDS 144KB -> 1 block/CU.
__global__ __launch_bounds__(512, 2) void fused_kernel(
    const float* __restrict__ z, const int* __restrict__ x, const int* __restrict__ y,
    const float* __restrict__ b1, const float* __restrict__ g1, const float* __restrict__ be1,
    const float* __restrict__ b2, const float* __restrict__ g2, const float* __restrict__ be2,
    const float* __restrict__ bh1, const float* __restrict__ Wh2, const float* __restrict__ bh2,
    const short* __restrict__ ws, float* __restrict__ out)
{
    __shared__ __align__(16) short scr[8 * 16 * 512];   // 128KB wave-private A-scratch
    __shared__ __align__(16) short bbuf[2][8 * 512];    // 2 x 8KB B chunk double-buffer

    int tid  = threadIdx.x;
    int wave = tid >> 6;
    int lane = tid & 63;
    int quad = lane >> 4;
    int l16  = lane & 15;
    int row0 = blockIdx.x * MT + wave * 16;   // this wave's global row base

    short* myscr = scr + wave * (16 * 512);

    floatx4 acc[32];   // 128 AGPRs (stage 3 uses acc[0..15])

    // ---- hoist z fragments (2 x K=32 slices for this wave's 16 rows) ----
    short8 azfr[2];
#pragma unroll
    for (int ks = 0; ks < 2; ks++) {
        const float* zp = z + (row0 + l16) * 64 + ks * 32 + quad * 8;
        floatx4 f0 = *(const floatx4*)zp;
        floatx4 f1 = *(const floatx4*)(zp + 4);
        uintx4 up;
        up[0] = cvtpk(f0[0], f0[1]); up[1] = cvtpk(f0[2], f0[3]);
        up[2] = cvtpk(f1[0], f1[1]); up[3] = cvtpk(f1[2], f1[3]);
        azfr[ks] = __builtin_bit_cast(short8, up);
    }

    // ---- prologue: stage chunk 0 ----
    gload16(ws + tid * 8, &bbuf[0][tid * 8]);
    __syncthreads();
    const short* wsp = ws + 4096;   // next-chunk stream pointer (flat: w1|w2|wh1)
    int cur = 0;

    // ======== stage 1: h1-pre = z @ W1  (8 chunks: ncg0..3 x ks0..1) ========
#pragma unroll
    for (int nt = 0; nt < 32; nt++) acc[nt] = (floatx4){0.f, 0.f, 0.f, 0.f};
#pragma unroll
    for (int c = 0; c < 8; c++) {
        int ncg = c >> 1, ks = c & 1;
        gload16(wsp + tid * 8, &bbuf[cur ^ 1][tid * 8]);   // prefetch (flows into w2)
        wsp += 4096;
#pragma unroll
        for (int ntl = 0; ntl < 8; ntl++) {
            short8 b = *(const short8*)&bbuf[cur][ntl * 512 + lane * 8];
            acc[ncg * 8 + ntl] =
                __builtin_amdgcn_mfma_f32_16x16x32_bf16(azfr[ks], b, acc[ncg * 8 + ntl], 0, 0, 0);
        }
        __syncthreads();
        cur ^= 1;
    }

    // ---- stage-1 epilogue: bias + LN (wave-local) + leaky -> scratch ----
    {
        floatx2 s2[2] = {}, q2[2] = {};
#pragma unroll
        for (int nt = 0; nt < 32; nt++) {
            float bv = b1[nt * 16 + l16];
            floatx2 bb = {bv, bv};
            floatx2 v01 = {acc[nt][0], acc[nt][1]};
            floatx2 v23 = {acc[nt][2], acc[nt][3]};
            v01 = pk_add(v01, bb); v23 = pk_add(v23, bb);
            acc[nt][0] = v01[0]; acc[nt][1] = v01[1];
            acc[nt][2] = v23[0]; acc[nt][3] = v23[1];
            s2[0] = pk_add(s2[0], v01); q2[0] = pk_fma(v01, v01, q2[0]);
            s2[1] = pk_add(s2[1], v23); q2[1] = pk_fma(v23, v23, q2[1]);
        }
#pragma unroll
        for (int pr = 0; pr < 2; pr++) {
            s2[pr][0] = red16(s2[pr][0]); s2[pr][1] = red16(s2[pr][1]);
            q2[pr][0] = red16(q2[pr][0]); q2[pr][1] = red16(q2[pr][1]);
        }
        float nm[4], rs[4];
#pragma unroll
        for (int r2 = 0; r2 < 4; r2++) {
            float s = bcast15(s2[r2 >> 1][r2 & 1]);
            float q = bcast15(q2[r2 >> 1][r2 & 1]);
            float mean = s * (1.f / 512.f);
            float var  = q * (1.f / 512.f) - mean * mean;
            nm[r2] = -mean; rs[r2] = rsqrtf(var + EPSV);
        }
#pragma unroll
        for (int seg = 0; seg < 4; seg++) {
            uintx4 upv[4];
#pragma unroll
            for (int sl = 0; sl < 4; sl++) {
                int nt = seg * 8 + sl * 2;
                floatx2 gg = {g1[nt * 16 + l16],  g1[nt * 16 + 16 + l16]};
                floatx2 bb = {be1[nt * 16 + l16], be1[nt * 16 + 16 + l16]};
#pragma unroll
                for (int r2 = 0; r2 < 4; r2++) {
                    floatx2 v = {acc[nt][r2], acc[nt + 1][r2]};
                    floatx2 t = pk_mul(pk_add(v, (floatx2){nm[r2], nm[r2]}),
                                       (floatx2){rs[r2], rs[r2]});
                    floatx2 f = pk_fma(t, gg, bb);
                    upv[r2][sl] = cvtpk(fmaxf(f[0], 0.2f * f[0]), fmaxf(f[1], 0.2f * f[1]));
                }
            }
#pragma unroll
            for (int r2 = 0; r2 < 4; r2++) {
                int row = quad * 4 + r2;
                int cb = l16 * 4 + seg;   // k' = l16*32 + seg*8
                *(uintx4*)&myscr[row * 512 + ((cb ^ (row & 7)) << 3)] = upv[r2];
            }
        }
    }

    // ======== stage 2: h2-pre = h1 @ W2  (64 chunks: ncg0..3 x ks0..15) ========
#pragma unroll
    for (int nt = 0; nt < 32; nt++) acc[nt] = (floatx4){0.f, 0.f, 0.f, 0.f};
#pragma unroll
    for (int ncg = 0; ncg < 4; ncg++) {
        for (int ks = 0; ks < 16; ks++) {
            gload16(wsp + tid * 8, &bbuf[cur ^ 1][tid * 8]);   // last iter prefetches wh1
            wsp += 4096;
            short8 afr = *(const short8*)&myscr[l16 * 512 + (((ks * 4 + quad) ^ (l16 & 7)) << 3)];
#pragma unroll
            for (int ntl = 0; ntl < 8; ntl++) {
                short8 b = *(const short8*)&bbuf[cur][ntl * 512 + lane * 8];
                acc[ncg * 8 + ntl] =
                    __builtin_amdgcn_mfma_f32_16x16x32_bf16(afr, b, acc[ncg * 8 + ntl], 0, 0, 0);
            }
            __syncthreads();
            cur ^= 1;
        }
    }

    // ---- stage-2 epilogue: bias + LN + leaky -> scratch ----
    {
        floatx2 s2[2] = {}, q2[2] = {};
#pragma unroll
        for (int nt = 0; nt < 32; nt++) {
            float bv = b2[nt * 16 + l16];
            floatx2 bb = {bv, bv};
            floatx2 v01 = {acc[nt][0], acc[nt][1]};
            floatx2 v23 = {acc[nt][2], acc[nt][3]};
            v01 = pk_add(v01, bb); v23 = pk_add(v23, bb);
            acc[nt][0] = v01[0]; acc[nt][1] = v01[1];
            acc[nt][2] = v23[0]; acc[nt][3] = v23[1];
            s2[0] = pk_add(s2[0], v01); q2[0] = pk_fma(v01, v01, q2[0]);
            s2[1] = pk_add(s2[1], v23); q2[1] = pk_fma(v23, v23, q2[1]);
        }
#pragma unroll
        for (int pr = 0; pr < 2; pr++) {
            s2[pr][0] = red16(s2[pr][0]); s2[pr][1] = red16(s2[pr][1]);
            q2[pr][0] = red16(q2[pr][0]); q2[pr][1] = red16(q2[pr][1]);
        }
        float nm[4], rs[4];
#pragma unroll
        for (int r2 = 0; r2 < 4; r2++) {
            float s = bcast15(s2[r2 >> 1][r2 & 1]);
            float q = bcast15(q2[r2 >> 1][r2 & 1]);
            float mean = s * (1.f / 512.f);
            float var  = q * (1.f / 512.f) - mean * mean;
            nm[r2] = -mean; rs[r2] = rsqrtf(var + EPSV);
        }
#pragma unroll
        for (int seg = 0; seg < 4; seg++) {
            uintx4 upv[4];
#pragma unroll
            for (int sl = 0; sl < 4; sl++) {
                int nt = seg * 8 + sl * 2;
                floatx2 gg = {g2[nt * 16 + l16],  g2[nt * 16 + 16 + l16]};
                floatx2 bb = {be2[nt * 16 + l16], be2[nt * 16 + 16 + l16]};
#pragma unroll
                for (int r2 = 0; r2 < 4; r2++) {
                    floatx2 v = {acc[nt][r2], acc[nt + 1][r2]};
                    floatx2 t = pk_mul(pk_add(v, (floatx2){nm[r2], nm[r2]}),
                                       (floatx2){rs[r2], rs[r2]});
                    floatx2 f = pk_fma(t, gg, bb);
                    upv[r2][sl] = cvtpk(fmaxf(f[0], 0.2f * f[0]), fmaxf(f[1], 0.2f * f[1]));
                }
            }
#pragma unroll
            for (int r2 = 0; r2 < 4; r2++) {
                int row = quad * 4 + r2;
                int cb = l16 * 4 + seg;
                *(uintx4*)&myscr[row * 512 + ((cb ^ (row & 7)) << 3)] = upv[r2];
            }
        }
    }

    // ======== stage 3: t = relu(h2 @ Wh1 + bh1), all 4 heads (32 chunks) ========
#pragma unroll
    for (int nt = 0; nt < 16; nt++) acc[nt] = (floatx4){0.f, 0.f, 0.f, 0.f};
#pragma unroll
    for (int ncg = 0; ncg < 2; ncg++) {
        for (int ks = 0; ks < 16; ks++) {
            if (!(ncg == 1 && ks == 15)) {                 // last chunk: nothing left
                gload16(wsp + tid * 8, &bbuf[cur ^ 1][tid * 8]);
                wsp += 4096;
            }
            short8 afr = *(const short8*)&myscr[l16 * 512 + (((ks * 4 + quad) ^ (l16 & 7)) << 3)];
#pragma unroll
            for (int ntl = 0; ntl < 8; ntl++) {
                short8 b = *(const short8*)&bbuf[cur][ntl * 512 + lane * 8];
                acc[ncg * 8 + ntl] =
                    __builtin_amdgcn_mfma_f32_16x16x32_bf16(afr, b, acc[ncg * 8 + ntl], 0, 0, 0);
            }
            __syncthreads();
            cur ^= 1;
        }
    }

    // ---- stage-3 epilogue: +bh1, relu, pack t -> scratch (k'3 = l16*16 + nt) ----
    {
#pragma unroll
        for (int seg = 0; seg < 2; seg++) {
            uintx4 upv[4];
#pragma unroll
            for (int sl = 0; sl < 4; sl++) {
                int nt = seg * 8 + sl * 2;
                floatx2 bb = {bh1[nt * 16 + l16], bh1[nt * 16 + 16 + l16]};
#pragma unroll
                for (int r2 = 0; r2 < 4; r2++) {
                    floatx2 v = pk_add((floatx2){acc[nt][r2], acc[nt + 1][r2]}, bb);
                    upv[r2][sl] = cvtpk(fmaxf(v[0], 0.f), fmaxf(v[1], 0.f));
                }
            }
#pragma unroll
            for (int r2 = 0; r2 < 4; r2++) {
                int row = quad * 4 + r2;
                int cb = l16 * 2 + seg;   // k'3 = l16*16 + seg*8
                *(uintx4*)&myscr[row * 512 + ((cb ^ (row & 7)) << 3)] = upv[r2];
            }
        }
    }
    // no barrier: scratch is wave-private; stage 4 reads own rows only

    // ======== stage 4: head select + logits + softmax (4 lanes per row) ========
    {
        int rl = lane >> 2, is = lane & 3;        // rl 0..15 local row
        int grow = row0 + rl;
        int kk = 2 * x[grow] + y[grow];
        float tv[16];
#pragma unroll
        for (int m = 0; m < 4; m++) {
            int k3 = (4 * is + m) * 16 + kk * 4;  // l16t = 4is+m, nt = kk*4+ntl
            int cb = k3 >> 3;
            int off = k3 & 7;                     // = (kk&1)*4
            shortx4 t4 = *(const shortx4*)&myscr[rl * 512 + ((cb ^ (rl & 7)) << 3) + off];
            tv[m * 4 + 0] = bf2f(t4[0]); tv[m * 4 + 1] = bf2f(t4[1]);
            tv[m * 4 + 2] = bf2f(t4[2]); tv[m * 4 + 3] = bf2f(t4[3]);
        }
        const float* wp = Wh2 + kk * 256;
        float lg0 = 0.f, lg1 = 0.f, lg2 = 0.f, lg3 = 0.f;
#pragma unroll
        for (int m = 0; m < 4; m++)
#pragma unroll
            for (int ntl = 0; ntl < 4; ntl++) {
                int dd = ntl * 16 + 4 * is + m;   // d = kk*64 + dd
                floatx4 w = *(const floatx4*)(wp + dd * 4);
                float t = tv[m * 4 + ntl];
                lg0 += t * w[0]; lg1 += t * w[1];
                lg2 += t * w[2]; lg3 += t * w[3];
            }
#pragma unroll
        for (int off = 1; off < 4; off <<= 1) {
            lg0 += __shfl_xor(lg0, off, 64);
            lg1 += __shfl_xor(lg1, off, 64);
            lg2 += __shfl_xor(lg2, off, 64);
            lg3 += __shfl_xor(lg3, off, 64);
        }
        if (is == 0) {
            lg0 += bh2[kk * 4 + 0]; lg1 += bh2[kk * 4 + 1];
            lg2 += bh2[kk * 4 + 2]; lg3 += bh2[kk * 4 + 3];
            float mmax = fmaxf(fmaxf(lg0, lg1), fmaxf(lg2, lg3));
            float e0 = __expf(lg0 - mmax), e1 = __expf(lg1 - mmax);
            float e2 = __expf(lg2 - mmax), e3 = __expf(lg3 - mmax);
            float inv = 1.f / (e0 + e1 + e2 + e3);
            floatx4 o = {e0 * inv, e1 * inv, e2 * inv, e3 * inv};
            *(floatx4*)(out + grow * 4) = o;
        }
    }
}

extern "C" void kernel_launch(void* const* d_in, const int* in_sizes, int n_in,
                              void* d_out, int out_size, void* d_ws, size_t ws_size,
                              hipStream_t stream) {
    const float* z   = (const float*)d_in[0];
    const int*   x   = (const int*)d_in[1];
    const int*   y   = (const int*)d_in[2];
    const float* W1  = (const float*)d_in[3];
    const float* b1  = (const float*)d_in[4];
    const float* g1  = (const float*)d_in[5];
    const float* be1 = (const float*)d_in[6];
    const float* W2  = (const float*)d_in[7];
    const float* b2  = (const float*)d_in[8];
    const float* g2  = (const float*)d_in[9];
    const float* be2 = (const float*)d_in[10];
    const float* Wh1 = (const float*)d_in[11];
    const float* bh1 = (const float*)d_in[12];
    const float* Wh2 = (const float*)d_in[13];
    const float* bh2 = (const float*)d_in[14];
    short* ws = (short*)d_ws;
    float* out = (float*)d_out;

    hipLaunchKernelGGL(convert_weights, dim3(1664), dim3(256), 0, stream, W1, W2, Wh1, ws);
    hipLaunchKernelGGL(fused_kernel, dim3(NBLK), dim3(512), 0, stream,
                       z, x, y, b1, g1, be1, b2, g2, be2, bh1, Wh2, bh2,
                       (const short*)ws, out);
}

// Round 6
// 434.997 us; speedup vs baseline: 1.1193x; 1.1193x over previous
//
#include <hip/hip_runtime.h>

#define NROWS 262144
#define MT 128                  // rows per block = shared A-tile; 2048 blocks exact
#define NBLK (NROWS / MT)
#define TS 520                  // tile row stride (shorts): 512 + 8 pad
#define EPSV 1e-5f

typedef __attribute__((ext_vector_type(8))) short short8;
typedef __attribute__((ext_vector_type(4))) float floatx4;
typedef __attribute__((ext_vector_type(2))) float floatx2;
typedef __attribute__((ext_vector_type(2))) unsigned int uintx2;

__device__ __forceinline__ unsigned short f2bf(float f) {
    unsigned u = __builtin_bit_cast(unsigned, f);
    u += 0x7fff + ((u >> 16) & 1);
    return (unsigned short)(u >> 16);
}
__device__ __forceinline__ float bf2f(short s) {
    unsigned u = ((unsigned)(unsigned short)s) << 16;
    return __builtin_bit_cast(float, u);
}
__device__ __forceinline__ unsigned cvtpk(float a, float b) {
    unsigned r;
    asm("v_cvt_pk_bf16_f32 %0, %1, %2" : "=v"(r) : "v"(a), "v"(b));
    return r;
}
__device__ __forceinline__ floatx2 pk_add(floatx2 a, floatx2 b) {
    floatx2 d; asm("v_pk_add_f32 %0, %1, %2" : "=v"(d) : "v"(a), "v"(b)); return d;
}
__device__ __forceinline__ floatx2 pk_mul(floatx2 a, floatx2 b) {
    floatx2 d; asm("v_pk_mul_f32 %0, %1, %2" : "=v"(d) : "v"(a), "v"(b)); return d;
}
__device__ __forceinline__ floatx2 pk_fma(floatx2 a, floatx2 b, floatx2 c) {
    floatx2 d; asm("v_pk_fma_f32 %0, %1, %2, %3" : "=v"(d) : "v"(a), "v"(b), "v"(c)); return d;
}
template<int C>
__device__ __forceinline__ float dpp_add(float v) {
    int t = __builtin_amdgcn_update_dpp(0, __builtin_bit_cast(int, v), C, 0xf, 0xf, true);
    return v + __builtin_bit_cast(float, t);
}
__device__ __forceinline__ float red16(float v) {
    v = dpp_add<0x111>(v);   // row_shr:1
    v = dpp_add<0x112>(v);   // row_shr:2
    v = dpp_add<0x114>(v);   // row_shr:4
    v = dpp_add<0x118>(v);   // row_shr:8
    return v;                // valid in l16==15
}

// ===== R6 weight layout: 64-col wave slabs, POSITION-permuted K =====
// Tile stores h at POSITION P (not actual col). Per 64-group g = P>>6,
// local p = P&63: actual col = g*64 + (p&3)*16 + (p>>2). The LN-writer
// (lane l16, ntl) thus writes its 4 values CONTIGUOUSLY at p = l16*4+ntl
// (one b64), and the MFMA A-reader reads 8 contiguous positions (b128).
// B bakes the same bijection: chunk holds W[perm(P)][n], lane-ordered
// [lane][j], P = ks*32 + (lane>>4)*8 + j.
//   w1  at 0      : c = (wn*2+ks)*4+ntl   (k natural: A = z), n = wn*64+ntl*16+l16
//   w2  at 32768  : c = (wn*16+ks)*4+ntl, k = perm(P),        n = wn*64+ntl*16+l16
//   wh1 at 294912 : c = (wn*16+ks)*2+ntl, k = perm(P), kk = wn>>1,
//                   d = (wn&1)*32+ntl*16+l16
// t-tile (stage 3 out) uses 32-group perm: P3 = w*32 + l16*2 + ntl holds
// d = (P3>>5)*32... inverse: p=P3&31 -> d = (p&1)*16 + (p>>1) within group.
__global__ void convert_weights(const float* __restrict__ W1, const float* __restrict__ W2,
                                const float* __restrict__ Wh1, short* __restrict__ ws) {
    int idx = blockIdx.x * 256 + threadIdx.x;
    int j = idx & 7, lane = (idx >> 3) & 63;
    int q = lane >> 4, l16 = lane & 15;
    if (idx < 32768) {
        int c = idx >> 9;                         // 0..63
        int ntl = c & 3, ks = (c >> 2) & 1, wn = c >> 3;
        int k = ks * 32 + q * 8 + j;              // natural
        int n = wn * 64 + ntl * 16 + l16;
        ws[idx] = (short)f2bf(W1[k * 512 + n]);
    } else if (idx < 294912) {
        int c = (idx - 32768) >> 9;               // 0..511
        int ntl = c & 3, ks = (c >> 2) & 15, wn = c >> 6;
        int P = ks * 32 + q * 8 + j;
        int p = P & 63;
        int k = (P >> 6) * 64 + (p & 3) * 16 + (p >> 2);   // perm
        int n = wn * 64 + ntl * 16 + l16;
        ws[idx] = (short)f2bf(W2[k * 512 + n]);
    } else if (idx < 425984) {
        int c = (idx - 294912) >> 9;              // 0..255
        int ntl = c & 1, ks = (c >> 1) & 15, wn = c >> 5;
        int P = ks * 32 + q * 8 + j;
        int p = P & 63;
        int k = (P >> 6) * 64 + (p & 3) * 16 + (p >> 2);   // perm
        int kk = wn >> 1;
        int d = (wn & 1) * 32 + ntl * 16 + l16;
        ws[idx] = (short)f2bf(Wh1[(kk * 512 + k) * 64 + d]);
    }
}

// R6: 8-wave N-split with 64-col slabs over MT=128 shared rows.
// B read direct from L2 by its OWNER wave only (832KB/block, no dup, no LDS
// staging, no K-loop barriers) -> per-CU B traffic 13.3MB -> 6.6MB vs R4,
// and each B-load feeds 8 MFMAs (was 4). A-tile block-shared in LDS (133KB).
// R5's LDS-staged B REVERTED (it moved B-reads to LDS at same volume and
// added 104 vmcnt-draining barriers: 434us vs R4's 338).
// acc 8x4 = 128 AGPR + ~110 VGPR -> 2 waves/SIMD; 1 block/CU (LDS 142KB).
__global__ __launch_bounds__(512, 2) void fused_kernel(
    const float* __restrict__ z, const int* __restrict__ x, const int* __restrict__ y,
    const float* __restrict__ b1, const float* __restrict__ g1, const float* __restrict__ be1,
    const float* __restrict__ b2, const float* __restrict__ g2, const float* __restrict__ be2,
    const float* __restrict__ bh1, const float* __restrict__ Wh2, const float* __restrict__ bh2,
    const short* __restrict__ ws, float* __restrict__ out)
{
    __shared__ __align__(16) short tile[MT * TS];   // 133,120 B: h1 -> h2 -> t
    __shared__ float psum[8][MT];                   // 4 KB per-wave partial sums
    __shared__ float psq[8][MT];                    // 4 KB partial sum-of-squares
    __shared__ float rmean[MT];                     // 512 B, NEGATED mean
    __shared__ float rrstd[MT];                     // 512 B

    int tid  = threadIdx.x;
    int wave = tid >> 6;
    int lane = tid & 63;
    int quad = lane >> 4;
    int l16  = lane & 15;
    int row0 = blockIdx.x * MT;

    const short* bbase1 = ws + wave * (8 * 512) + lane * 8;
    const short* bbase2 = ws + 32768 + wave * (64 * 512) + lane * 8;
    const short* bbase3 = ws + 294912 + wave * (32 * 512) + lane * 8;

    floatx4 acc[8][4];   // 128 AGPRs; stage 3 uses acc[mt][0..1]

    // ================= stage 1: h1 = LN(z @ W1 + b1) -> leaky =================
#pragma unroll
    for (int mt = 0; mt < 8; mt++)
#pragma unroll
        for (int ntl = 0; ntl < 4; ntl++) acc[mt][ntl] = (floatx4){0.f, 0.f, 0.f, 0.f};

    __builtin_amdgcn_s_setprio(1);
#pragma unroll
    for (int ks = 0; ks < 2; ks++) {
        short8 afr[8];
#pragma unroll
        for (int mt = 0; mt < 8; mt++) {
            const float* zp = z + (row0 + mt * 16 + l16) * 64 + ks * 32 + quad * 8;
            floatx4 f0 = *(const floatx4*)zp;
            floatx4 f1 = *(const floatx4*)(zp + 4);
            uintx2 lo = {cvtpk(f0[0], f0[1]), cvtpk(f0[2], f0[3])};
            uintx2 hi = {cvtpk(f1[0], f1[1]), cvtpk(f1[2], f1[3])};
            afr[mt] = __builtin_bit_cast(short8,
                (__attribute__((ext_vector_type(4))) unsigned int){lo[0], lo[1], hi[0], hi[1]});
        }
#pragma unroll
        for (int ntl = 0; ntl < 4; ntl++) {
            short8 b = *(const short8*)(bbase1 + (ks * 4 + ntl) * 512);
#pragma unroll
            for (int mt = 0; mt < 8; mt++)
                acc[mt][ntl] = __builtin_amdgcn_mfma_f32_16x16x32_bf16(afr[mt], b, acc[mt][ntl], 0, 0, 0);
        }
    }
    __builtin_amdgcn_s_setprio(0);

    // ---- stage-1 epilogue: bias + stats (DPP) -> pstats -> LN apply -> tile ----
    {
        float bv[4];
#pragma unroll
        for (int ntl = 0; ntl < 4; ntl++) bv[ntl] = b1[wave * 64 + ntl * 16 + l16];
#pragma unroll
        for (int mt = 0; mt < 8; mt++) {
            floatx2 s01 = {0.f, 0.f}, s23 = {0.f, 0.f}, q01 = {0.f, 0.f}, q23 = {0.f, 0.f};
#pragma unroll
            for (int ntl = 0; ntl < 4; ntl++) {
                floatx2 bb = {bv[ntl], bv[ntl]};
                floatx2 v01 = pk_add((floatx2){acc[mt][ntl][0], acc[mt][ntl][1]}, bb);
                floatx2 v23 = pk_add((floatx2){acc[mt][ntl][2], acc[mt][ntl][3]}, bb);
                acc[mt][ntl][0] = v01[0]; acc[mt][ntl][1] = v01[1];
                acc[mt][ntl][2] = v23[0]; acc[mt][ntl][3] = v23[1];
                s01 = pk_add(s01, v01); q01 = pk_fma(v01, v01, q01);
                s23 = pk_add(s23, v23); q23 = pk_fma(v23, v23, q23);
            }
            s01[0] = red16(s01[0]); s01[1] = red16(s01[1]);
            s23[0] = red16(s23[0]); s23[1] = red16(s23[1]);
            q01[0] = red16(q01[0]); q01[1] = red16(q01[1]);
            q23[0] = red16(q23[0]); q23[1] = red16(q23[1]);
            if (l16 == 15) {
                int row = mt * 16 + quad * 4;
                *(floatx2*)&psum[wave][row]     = s01;
                *(floatx2*)&psum[wave][row + 2] = s23;
                *(floatx2*)&psq[wave][row]      = q01;
                *(floatx2*)&psq[wave][row + 2]  = q23;
            }
        }
    }
    __syncthreads();
    if (tid < MT) {
        float s = 0.f, q = 0.f;
#pragma unroll
        for (int w = 0; w < 8; w++) { s += psum[w][tid]; q += psq[w][tid]; }
        float mean = s * (1.f / 512.f);
        float var  = q * (1.f / 512.f) - mean * mean;
        rmean[tid] = -mean;
        rrstd[tid] = rsqrtf(var + EPSV);
    }
    __syncthreads();
    {
        float gv[4], bev[4];
#pragma unroll
        for (int ntl = 0; ntl < 4; ntl++) {
            int col = wave * 64 + ntl * 16 + l16;
            gv[ntl] = g1[col]; bev[ntl] = be1[col];
        }
#pragma unroll
        for (int mt = 0; mt < 8; mt++) {
            int rb = mt * 16 + quad * 4;
            floatx2 nm01 = *(const floatx2*)&rmean[rb];
            floatx2 nm23 = *(const floatx2*)&rmean[rb + 2];
            floatx2 rs01 = *(const floatx2*)&rrstd[rb];
            floatx2 rs23 = *(const floatx2*)&rrstd[rb + 2];
            float fv[4][4];
#pragma unroll
            for (int ntl = 0; ntl < 4; ntl++) {
                floatx2 gg = {gv[ntl], gv[ntl]}, bb = {bev[ntl], bev[ntl]};
                floatx2 t01 = pk_fma(pk_mul(pk_add((floatx2){acc[mt][ntl][0], acc[mt][ntl][1]}, nm01), rs01), gg, bb);
                floatx2 t23 = pk_fma(pk_mul(pk_add((floatx2){acc[mt][ntl][2], acc[mt][ntl][3]}, nm23), rs23), gg, bb);
                fv[ntl][0] = fmaxf(t01[0], 0.2f * t01[0]);
                fv[ntl][1] = fmaxf(t01[1], 0.2f * t01[1]);
                fv[ntl][2] = fmaxf(t23[0], 0.2f * t23[0]);
                fv[ntl][3] = fmaxf(t23[1], 0.2f * t23[1]);
            }
#pragma unroll
            for (int r2 = 0; r2 < 4; r2++) {
                uintx2 up = {cvtpk(fv[0][r2], fv[1][r2]), cvtpk(fv[2][r2], fv[3][r2])};
                *(uintx2*)&tile[(rb + r2) * TS + wave * 64 + l16 * 4] = up;
            }
        }
    }
    __syncthreads();

    // ================= stage 2: h2 = LN(h1 @ W2 + b2) -> leaky =================
#pragma unroll
    for (int mt = 0; mt < 8; mt++)
#pragma unroll
        for (int ntl = 0; ntl < 4; ntl++) acc[mt][ntl] = (floatx4){0.f, 0.f, 0.f, 0.f};

    __builtin_amdgcn_s_setprio(1);
    for (int ks = 0; ks < 16; ks++) {
        short8 afr[8];
#pragma unroll
        for (int mt = 0; mt < 8; mt++)
            afr[mt] = *(const short8*)&tile[(mt * 16 + l16) * TS + ks * 32 + quad * 8];
#pragma unroll
        for (int ntl = 0; ntl < 4; ntl++) {
            short8 b = *(const short8*)(bbase2 + (ks * 4 + ntl) * 512);
#pragma unroll
            for (int mt = 0; mt < 8; mt++)
                acc[mt][ntl] = __builtin_amdgcn_mfma_f32_16x16x32_bf16(afr[mt], b, acc[mt][ntl], 0, 0, 0);
        }
    }
    __builtin_amdgcn_s_setprio(0);

    // ---- stage-2 epilogue (same shape as stage-1) ----
    {
        float bv[4];
#pragma unroll
        for (int ntl = 0; ntl < 4; ntl++) bv[ntl] = b2[wave * 64 + ntl * 16 + l16];
#pragma unroll
        for (int mt = 0; mt < 8; mt++) {
            floatx2 s01 = {0.f, 0.f}, s23 = {0.f, 0.f}, q01 = {0.f, 0.f}, q23 = {0.f, 0.f};
#pragma unroll
            for (int ntl = 0; ntl < 4; ntl++) {
                floatx2 bb = {bv[ntl], bv[ntl]};
                floatx2 v01 = pk_add((floatx2){acc[mt][ntl][0], acc[mt][ntl][1]}, bb);
                floatx2 v23 = pk_add((floatx2){acc[mt][ntl][2], acc[mt][ntl][3]}, bb);
                acc[mt][ntl][0] = v01[0]; acc[mt][ntl][1] = v01[1];
                acc[mt][ntl][2] = v23[0]; acc[mt][ntl][3] = v23[1];
                s01 = pk_add(s01, v01); q01 = pk_fma(v01, v01, q01);
                s23 = pk_add(s23, v23); q23 = pk_fma(v23, v23, q23);
            }
            s01[0] = red16(s01[0]); s01[1] = red16(s01[1]);
            s23[0] = red16(s23[0]); s23[1] = red16(s23[1]);
            q01[0] = red16(q01[0]); q01[1] = red16(q01[1]);
            q23[0] = red16(q23[0]); q23[1] = red16(q23[1]);
            if (l16 == 15) {
                int row = mt * 16 + quad * 4;
                *(floatx2*)&psum[wave][row]     = s01;
                *(floatx2*)&psum[wave][row + 2] = s23;
                *(floatx2*)&psq[wave][row]      = q01;
                *(floatx2*)&psq[wave][row + 2]  = q23;
            }
        }
    }
    __syncthreads();
    if (tid < MT) {
        float s = 0.f, q = 0.f;
#pragma unroll
        for (int w = 0; w < 8; w++) { s += psum[w][tid]; q += psq[w][tid]; }
        float mean = s * (1.f / 512.f);
        float var  = q * (1.f / 512.f) - mean * mean;
        rmean[tid] = -mean;
        rrstd[tid] = rsqrtf(var + EPSV);
    }
    __syncthreads();
    {
        float gv[4], bev[4];
#pragma unroll
        for (int ntl = 0; ntl < 4; ntl++) {
            int col = wave * 64 + ntl * 16 + l16;
            gv[ntl] = g2[col]; bev[ntl] = be2[col];
        }
#pragma unroll
        for (int mt = 0; mt < 8; mt++) {
            int rb = mt * 16 + quad * 4;
            floatx2 nm01 = *(const floatx2*)&rmean[rb];
            floatx2 nm23 = *(const floatx2*)&rmean[rb + 2];
            floatx2 rs01 = *(const floatx2*)&rrstd[rb];
            floatx2 rs23 = *(const floatx2*)&rrstd[rb + 2];
            float fv[4][4];
#pragma unroll
            for (int ntl = 0; ntl < 4; ntl++) {
                floatx2 gg = {gv[ntl], gv[ntl]}, bb = {bev[ntl], bev[ntl]};
                floatx2 t01 = pk_fma(pk_mul(pk_add((floatx2){acc[mt][ntl][0], acc[mt][ntl][1]}, nm01), rs01), gg, bb);
                floatx2 t23 = pk_fma(pk_mul(pk_add((floatx2){acc[mt][ntl][2], acc[mt][ntl][3]}, nm23), rs23), gg, bb);
                fv[ntl][0] = fmaxf(t01[0], 0.2f * t01[0]);
                fv[ntl][1] = fmaxf(t01[1], 0.2f * t01[1]);
                fv[ntl][2] = fmaxf(t23[0], 0.2f * t23[0]);
                fv[ntl][3] = fmaxf(t23[1], 0.2f * t23[1]);
            }
#pragma unroll
            for (int r2 = 0; r2 < 4; r2++) {
                uintx2 up = {cvtpk(fv[0][r2], fv[1][r2]), cvtpk(fv[2][r2], fv[3][r2])};
                *(uintx2*)&tile[(rb + r2) * TS + wave * 64 + l16 * 4] = up;
            }
        }
    }
    __syncthreads();

    // ======== stage 3: t = relu(h2 @ Wh1 + bh1), wave owns 32 t-cols ========
#pragma unroll
    for (int mt = 0; mt < 8; mt++)
#pragma unroll
        for (int ntl = 0; ntl < 2; ntl++) acc[mt][ntl] = (floatx4){0.f, 0.f, 0.f, 0.f};

    __builtin_amdgcn_s_setprio(1);
    for (int ks = 0; ks < 16; ks++) {
        short8 afr[8];
#pragma unroll
        for (int mt = 0; mt < 8; mt++)
            afr[mt] = *(const short8*)&tile[(mt * 16 + l16) * TS + ks * 32 + quad * 8];
#pragma unroll
        for (int ntl = 0; ntl < 2; ntl++) {
            short8 b = *(const short8*)(bbase3 + (ks * 2 + ntl) * 512);
#pragma unroll
            for (int mt = 0; mt < 8; mt++)
                acc[mt][ntl] = __builtin_amdgcn_mfma_f32_16x16x32_bf16(afr[mt], b, acc[mt][ntl], 0, 0, 0);
        }
    }
    __builtin_amdgcn_s_setprio(0);
    __syncthreads();   // all waves' stage-3 tile reads done before t overwrites

    // ---- stage-3 epilogue: +bh1, relu -> t at P3 = wave*32 + l16*2 + ntl ----
    {
        float bh1v[2];
#pragma unroll
        for (int ntl = 0; ntl < 2; ntl++) bh1v[ntl] = bh1[wave * 32 + ntl * 16 + l16];
#pragma unroll
        for (int mt = 0; mt < 8; mt++)
#pragma unroll
            for (int r2 = 0; r2 < 4; r2++) {
                int row = mt * 16 + quad * 4 + r2;
                float f0 = acc[mt][0][r2] + bh1v[0];
                float f1 = acc[mt][1][r2] + bh1v[1];
                f0 = (f0 > 0.f) ? f0 : 0.f;
                f1 = (f1 > 0.f) ? f1 : 0.f;
                *(unsigned int*)&tile[row * TS + wave * 32 + l16 * 2] = cvtpk(f0, f1);
            }
    }
    __syncthreads();

    // ======== stage 4: head select + logits + softmax (4 threads/row) ========
    // thread `is` reads 16 contiguous positions [kk*64 + is*16, +16); element
    // u = is*16+e maps to d = (u>>5)*32 + (u&1)*16 + ((u>>1)&15).
    {
        int r = tid >> 2, is = tid & 3;           // r 0..127
        int grow = row0 + r;
        int kk = 2 * x[grow] + y[grow];
        const short* tp = &tile[r * TS + kk * 64 + is * 16];
        short8 ta = *(const short8*)tp;
        short8 tb = *(const short8*)(tp + 8);
        const float* wp = Wh2 + kk * 256;
        float lg0 = 0.f, lg1 = 0.f, lg2 = 0.f, lg3 = 0.f;
#pragma unroll
        for (int e = 0; e < 8; e++) {
            int u = is * 16 + e;
            int d = (u >> 5) * 32 + (u & 1) * 16 + ((u >> 1) & 15);
            float t0 = bf2f(ta[e]);
            floatx4 w0 = *(const floatx4*)(wp + d * 4);
            lg0 += t0 * w0[0]; lg1 += t0 * w0[1];
            lg2 += t0 * w0[2]; lg3 += t0 * w0[3];
        }
#pragma unroll
        for (int e = 0; e < 8; e++) {
            int u = is * 16 + 8 + e;
            int d = (u >> 5) * 32 + (u & 1) * 16 + ((u >> 1) & 15);
            float t1 = bf2f(tb[e]);
            floatx4 w1 = *(const floatx4*)(wp + d * 4);
            lg0 += t1 * w1[0]; lg1 += t1 * w1[1];
            lg2 += t1 * w1[2]; lg3 += t1 * w1[3];
        }
#pragma unroll
        for (int off = 1; off < 4; off <<= 1) {
            lg0 += __shfl_xor(lg0, off, 64);
            lg1 += __shfl_xor(lg1, off, 64);
            lg2 += __shfl_xor(lg2, off, 64);
            lg3 += __shfl_xor(lg3, off, 64);
        }
        if (is == 0) {
            lg0 += bh2[kk * 4 + 0]; lg1 += bh2[kk * 4 + 1];
            lg2 += bh2[kk * 4 + 2]; lg3 += bh2[kk * 4 + 3];
            float m = fmaxf(fmaxf(lg0, lg1), fmaxf(lg2, lg3));
            float e0 = __expf(lg0 - m), e1 = __expf(lg1 - m);
            float e2 = __expf(lg2 - m), e3 = __expf(lg3 - m);
            float inv = 1.f / (e0 + e1 + e2 + e3);
            floatx4 o = {e0 * inv, e1 * inv, e2 * inv, e3 * inv};
            *(floatx4*)(out + grow * 4) = o;
        }
    }
}

extern "C" void kernel_launch(void* const* d_in, const int* in_sizes, int n_in,
                              void* d_out, int out_size, void* d_ws, size_t ws_size,
                              hipStream_t stream) {
    const float* z   = (const float*)d_in[0];
    const int*   x   = (const int*)d_in[1];
    const int*   y   = (const int*)d_in[2];
    const float* W1  = (const float*)d_in[3];
    const float* b1  = (const float*)d_in[4];
    const float* g1  = (const float*)d_in[5];
    const float* be1 = (const float*)d_in[6];
    const float* W2  = (const float*)d_in[7];
    const float* b2  = (const float*)d_in[8];
    const float* g2  = (const float*)d_in[9];
    const float* be2 = (const float*)d_in[10];
    const float* Wh1 = (const float*)d_in[11];
    const float* bh1 = (const float*)d_in[12];
    const float* Wh2 = (const float*)d_in[13];
    const float* bh2 = (const float*)d_in[14];
    short* ws = (short*)d_ws;
    float* out = (float*)d_out;

    hipLaunchKernelGGL(convert_weights, dim3(1664), dim3(256), 0, stream, W1, W2, Wh1, ws);
    hipLaunchKernelGGL(fused_kernel, dim3(NBLK), dim3(512), 0, stream,
                       z, x, y, b1, g1, be1, b2, g2, be2, bh1, Wh2, bh2,
                       (const short*)ws, out);
}